// Round 1
// baseline (106.329 us; speedup 1.0000x reference)
//
#include <hip/hip_runtime.h>

#define B_   64
#define C_   12
#define NC_  16
#define N0_  2048
#define N1_  1000
#define N2_  500
#define N3_  100

__device__ __forceinline__ float wred(float v) {
#pragma unroll
    for (int off = 32; off > 0; off >>= 1) v += __shfl_xor(v, off, 64);
    return v;
}

// ---------------- layer 1 (class branch): h1[b][j] = relu(x[b]·W1b[c][j] + b1b[c][j]) ----------
// grid (125, 12), block 256. 8 rows/block (2 per wave), K = 2048.
__global__ __launch_bounds__(256, 2)
void k_l1b(const float* __restrict__ x, const int* __restrict__ cls,
           const float* __restrict__ W1b, const float* __restrict__ b1b,
           float* __restrict__ h1) {
    const int c    = blockIdx.y;
    const int jt   = blockIdx.x;
    const int tid  = threadIdx.x;
    const int lane = tid & 63;
    const int wave = tid >> 6;

    __shared__ int   s_list[B_];
    __shared__ int   s_cnt;
    __shared__ float s_x[8][N0_];

    if (wave == 0) {
        bool mine = (cls[lane] == c);
        unsigned long long m = __ballot(mine);
        if (mine) s_list[__popcll(m & ((1ull << lane) - 1ull))] = lane;
        if (lane == 0) s_cnt = (int)__popcll(m);
    }
    __syncthreads();
    const int cnt = s_cnt;
    if (cnt == 0) return;

    const int j0 = jt * 8 + wave * 2;           // rows j0, j0+1  (always < 1000)
    const float4* wr0 = (const float4*)(W1b + ((size_t)c * N1_ + j0) * N0_);
    const float4* wr1 = wr0 + (N0_ / 4);

    for (int bc = 0; bc < cnt; bc += 8) {
        const int nb = (cnt - bc < 8) ? (cnt - bc) : 8;
        __syncthreads();
        for (int r = wave; r < nb; r += 4) {
            const float4* src = (const float4*)(x + (size_t)s_list[bc + r] * N0_);
            float4* dst = (float4*)(s_x[r]);
            for (int f = lane; f < N0_ / 4; f += 64) dst[f] = src[f];
        }
        __syncthreads();

        float4 w0[8], w1[8];
#pragma unroll
        for (int f = 0; f < 8; ++f) {
            const int idx = f * 64 + lane;
            w0[f] = wr0[idx];
            w1[f] = wr1[idx];
        }
        for (int i = 0; i < nb; ++i) {
            const float4* xr = (const float4*)(s_x[i]);
            float a0 = 0.f, a1 = 0.f;
#pragma unroll
            for (int f = 0; f < 8; ++f) {
                const float4 xv = xr[f * 64 + lane];
                a0 += w0[f].x * xv.x + w0[f].y * xv.y + w0[f].z * xv.z + w0[f].w * xv.w;
                a1 += w1[f].x * xv.x + w1[f].y * xv.y + w1[f].z * xv.z + w1[f].w * xv.w;
            }
            const float s0 = wred(a0);
            const float s1 = wred(a1);
            if (lane == 0) {
                const int b = s_list[bc + i];
                float v0 = s0 + b1b[c * N1_ + j0];
                float v1 = s1 + b1b[c * N1_ + j0 + 1];
                h1[(size_t)b * N1_ + j0]     = v0 > 0.f ? v0 : 0.f;
                h1[(size_t)b * N1_ + j0 + 1] = v1 > 0.f ? v1 : 0.f;
            }
        }
    }
}

// ---------------- layer 2 (class branch): h2[b][k] = relu(h1[b]·W2b[c][k] + b2b[c][k]) ----------
// grid (63, 12), block 256. 8 rows/block, K = 1000 (padded to 1024 in LDS).
__global__ __launch_bounds__(256, 2)
void k_l2b(const float* __restrict__ h1, const int* __restrict__ cls,
           const float* __restrict__ W2b, const float* __restrict__ b2b,
           float* __restrict__ h2) {
    const int c    = blockIdx.y;
    const int jt   = blockIdx.x;
    const int tid  = threadIdx.x;
    const int lane = tid & 63;
    const int wave = tid >> 6;

    __shared__ int   s_list[B_];
    __shared__ int   s_cnt;
    __shared__ float s_x[8][1024];

    if (wave == 0) {
        bool mine = (cls[lane] == c);
        unsigned long long m = __ballot(mine);
        if (mine) s_list[__popcll(m & ((1ull << lane) - 1ull))] = lane;
        if (lane == 0) s_cnt = (int)__popcll(m);
    }
    __syncthreads();
    const int cnt = s_cnt;
    if (cnt == 0) return;

    const int j0  = jt * 8 + wave * 2;          // rows j0, j0+1 (may exceed 499)
    const bool v0 = (j0 < N2_), v1 = (j0 + 1 < N2_);
    const int j0c = v0 ? j0 : N2_ - 1;
    const int j1c = v1 ? j0 + 1 : N2_ - 1;
    const float4* wr0 = (const float4*)(W2b + ((size_t)c * N2_ + j0c) * N1_);
    const float4* wr1 = (const float4*)(W2b + ((size_t)c * N2_ + j1c) * N1_);

    float4 w0[4], w1[4];
#pragma unroll
    for (int f = 0; f < 4; ++f) {
        const int idx = f * 64 + lane;          // float4 index, valid if < 250
        if (idx < N1_ / 4) { w0[f] = wr0[idx]; w1[f] = wr1[idx]; }
        else { w0[f] = make_float4(0.f, 0.f, 0.f, 0.f); w1[f] = w0[f]; }
    }

    for (int bc = 0; bc < cnt; bc += 8) {
        const int nb = (cnt - bc < 8) ? (cnt - bc) : 8;
        __syncthreads();
        for (int r = wave; r < nb; r += 4) {
            const float4* src = (const float4*)(h1 + (size_t)s_list[bc + r] * N1_);
            float4* dst = (float4*)(s_x[r]);
            for (int f = lane; f < 256; f += 64) dst[f] = src[f < N1_ / 4 ? f : 0];
        }
        __syncthreads();

        for (int i = 0; i < nb; ++i) {
            const float4* xr = (const float4*)(s_x[i]);
            float a0 = 0.f, a1 = 0.f;
#pragma unroll
            for (int f = 0; f < 4; ++f) {
                const float4 xv = xr[f * 64 + lane];
                a0 += w0[f].x * xv.x + w0[f].y * xv.y + w0[f].z * xv.z + w0[f].w * xv.w;
                a1 += w1[f].x * xv.x + w1[f].y * xv.y + w1[f].z * xv.z + w1[f].w * xv.w;
            }
            const float s0 = wred(a0);
            const float s1 = wred(a1);
            if (lane == 0) {
                const int b = s_list[bc + i];
                if (v0) { float v = s0 + b2b[c * N2_ + j0];     h2[(size_t)b * N2_ + j0]     = v > 0.f ? v : 0.f; }
                if (v1) { float v = s1 + b2b[c * N2_ + j0 + 1]; h2[(size_t)b * N2_ + j0 + 1] = v > 0.f ? v : 0.f; }
            }
        }
    }
}

// ---------------- layer 3 + argmax: y1[b][m], pose, expert select ----------
// grid 64, block 64 (one wave per b).
__global__ void k_l3b(const float* __restrict__ h2, const int* __restrict__ cls,
                      const float* __restrict__ W3b, const float* __restrict__ b3b,
                      float* __restrict__ out_y1, int* __restrict__ eb) {
    const int b    = blockIdx.x;
    const int lane = threadIdx.x;
    const int c    = cls[b];
    const float* h = h2 + (size_t)b * N2_;

    float best = -1e30f;
    int bestm = 0;
#pragma unroll 1
    for (int m = 0; m < NC_; ++m) {
        const float* wrow = W3b + ((size_t)c * NC_ + m) * N2_;
        float a = 0.f;
        for (int k = lane; k < N2_; k += 64) a += h[k] * wrow[k];
        const float s = wred(a) + b3b[c * NC_ + m];   // identical on all lanes
        if (lane == 0) out_y1[b * NC_ + m] = s;
        if (s > best) { best = s; bestm = m; }        // first-occurrence argmax
    }
    if (lane == 0) eb[b] = c * NC_ + bestm;
}

// ---------------- r-path layer 1, only the selected expert ----------
// grid (13, 64), block 256. 8 rows/block, K = 2048, rows j < 100.
__global__ __launch_bounds__(256, 2)
void k_l1r(const float* __restrict__ x, const int* __restrict__ eb,
           const float* __restrict__ W1r, const float* __restrict__ b1r,
           float* __restrict__ r) {
    const int b    = blockIdx.y;
    const int jt   = blockIdx.x;
    const int tid  = threadIdx.x;
    const int lane = tid & 63;
    const int wave = tid >> 6;
    const int e    = eb[b];

    __shared__ float s_x[N0_];
    {
        const float4* src = (const float4*)(x + (size_t)b * N0_);
        float4* dst = (float4*)s_x;
        for (int f = tid; f < N0_ / 4; f += 256) dst[f] = src[f];
    }
    __syncthreads();

    const int j0  = jt * 8 + wave * 2;
    const bool v0 = (j0 < N3_), v1 = (j0 + 1 < N3_);
    const int j0c = v0 ? j0 : N3_ - 1;
    const int j1c = v1 ? j0 + 1 : N3_ - 1;
    const float4* wr0 = (const float4*)(W1r + ((size_t)e * N3_ + j0c) * N0_);
    const float4* wr1 = (const float4*)(W1r + ((size_t)e * N3_ + j1c) * N0_);

    float4 w0[8], w1[8];
#pragma unroll
    for (int f = 0; f < 8; ++f) {
        const int idx = f * 64 + lane;
        w0[f] = wr0[idx];
        w1[f] = wr1[idx];
    }
    const float4* xr = (const float4*)s_x;
    float a0 = 0.f, a1 = 0.f;
#pragma unroll
    for (int f = 0; f < 8; ++f) {
        const float4 xv = xr[f * 64 + lane];
        a0 += w0[f].x * xv.x + w0[f].y * xv.y + w0[f].z * xv.z + w0[f].w * xv.w;
        a1 += w1[f].x * xv.x + w1[f].y * xv.y + w1[f].z * xv.z + w1[f].w * xv.w;
    }
    const float s0 = wred(a0);
    const float s1 = wred(a1);
    if (lane == 0) {
        if (v0) { float v = s0 + b1r[e * N3_ + j0];     r[b * 128 + j0]     = v > 0.f ? v : 0.f; }
        if (v1) { float v = s1 + b1r[e * N3_ + j0 + 1]; r[b * 128 + j0 + 1] = v > 0.f ? v : 0.f; }
    }
}

// ---------------- r-path layer 2 head: y2[b][d] ----------
// grid 64, block 64.
__global__ void k_l2r(const float* __restrict__ r, const int* __restrict__ eb,
                      const float* __restrict__ W2r, const float* __restrict__ b2r,
                      float* __restrict__ out_y2) {
    const int b    = blockIdx.x;
    const int lane = threadIdx.x;
    const int e    = eb[b];
    const float* rb = r + b * 128;
#pragma unroll 1
    for (int d = 0; d < 3; ++d) {
        const float* wrow = W2r + ((size_t)e * 3 + d) * N3_;
        float a = 0.f;
        for (int k = lane; k < N3_; k += 64) a += rb[k] * wrow[k];
        const float s = wred(a);
        if (lane == 0) out_y2[b * 3 + d] = s + b2r[e * 3 + d];
    }
}

extern "C" void kernel_launch(void* const* d_in, const int* in_sizes, int n_in,
                              void* d_out, int out_size, void* d_ws, size_t ws_size,
                              hipStream_t stream) {
    const float* x   = (const float*)d_in[0];
    const int*   cls = (const int*)  d_in[1];
    const float* W1b = (const float*)d_in[2];
    const float* b1b = (const float*)d_in[3];
    const float* W2b = (const float*)d_in[4];
    const float* b2b = (const float*)d_in[5];
    const float* W3b = (const float*)d_in[6];
    const float* b3b = (const float*)d_in[7];
    const float* W1r = (const float*)d_in[8];
    const float* b1r = (const float*)d_in[9];
    const float* W2r = (const float*)d_in[10];
    const float* b2r = (const float*)d_in[11];

    float* out = (float*)d_out;            // y1: [0,1024), y2: [1024,1216)
    char*  ws  = (char*)d_ws;
    float* h1  = (float*)(ws);             // 64*1000*4 = 256000 B
    float* h2  = (float*)(ws + 256000);    // 64*500*4  = 128000 B
    float* r   = (float*)(ws + 384000);    // 64*128*4  =  32768 B
    int*   eb  = (int*)  (ws + 416768);    // 64*4

    hipLaunchKernelGGL(k_l1b, dim3(125, 12), dim3(256), 0, stream, x, cls, W1b, b1b, h1);
    hipLaunchKernelGGL(k_l2b, dim3(63, 12),  dim3(256), 0, stream, h1, cls, W2b, b2b, h2);
    hipLaunchKernelGGL(k_l3b, dim3(64),      dim3(64),  0, stream, h2, cls, W3b, b3b, out, eb);
    hipLaunchKernelGGL(k_l1r, dim3(13, 64),  dim3(256), 0, stream, x, eb, W1r, b1r, r);
    hipLaunchKernelGGL(k_l2r, dim3(64),      dim3(64),  0, stream, r, eb, W2r, b2r, out + B_ * NC_);
}

// Round 2
// 90.685 us; speedup vs baseline: 1.1725x; 1.1725x over previous
//
#include <hip/hip_runtime.h>

#define B_   64
#define C_   12
#define NC_  16
#define N0_  2048
#define N1_  1000
#define N2_  500
#define N3_  100

__device__ __forceinline__ float wred(float v) {
#pragma unroll
    for (int off = 32; off > 0; off >>= 1) v += __shfl_xor(v, off, 64);
    return v;
}

// ---------------- layer 1 (class branch): h1[b][j] = relu(x[b]·W1b[c][j] + b1b[c][j])
// grid (125, 12), block 256. 2 rows/wave, no LDS, no syncthreads.
// Each wave builds the class's batch list privately via ballot (B == wavefront size).
__global__ __launch_bounds__(256)
void k_l1b(const float* __restrict__ x, const int* __restrict__ cls,
           const float* __restrict__ W1b, const float* __restrict__ b1b,
           float* __restrict__ h1) {
    const int c    = blockIdx.y;
    const int lane = threadIdx.x & 63;
    const int wave = threadIdx.x >> 6;

    const unsigned long long m = __ballot(cls[lane] == c);
    if (m == 0ull) return;

    const int j0 = blockIdx.x * 8 + wave * 2;            // rows j0, j0+1 (< 1000 always)
    const float4* wr0 = (const float4*)(W1b + ((size_t)c * N1_ + j0) * N0_);
    const float4* wr1 = wr0 + (N0_ / 4);

    float4 w0[8], w1[8];
#pragma unroll
    for (int f = 0; f < 8; ++f) {
        const int idx = f * 64 + lane;
        w0[f] = wr0[idx];
        w1[f] = wr1[idx];
    }
    const float bias0 = b1b[c * N1_ + j0];
    const float bias1 = b1b[c * N1_ + j0 + 1];

    for (unsigned long long mm = m; mm; mm &= (mm - 1ull)) {
        const int b = (int)__builtin_ctzll(mm);
        const float4* xr = (const float4*)(x + (size_t)b * N0_);
        float a0 = 0.f, a1 = 0.f;
#pragma unroll
        for (int f = 0; f < 8; ++f) {
            const float4 xv = xr[f * 64 + lane];
            a0 += w0[f].x * xv.x + w0[f].y * xv.y + w0[f].z * xv.z + w0[f].w * xv.w;
            a1 += w1[f].x * xv.x + w1[f].y * xv.y + w1[f].z * xv.z + w1[f].w * xv.w;
        }
        const float s0 = wred(a0);
        const float s1 = wred(a1);
        if (lane == 0) {
            h1[(size_t)b * N1_ + j0]     = fmaxf(s0 + bias0, 0.f);
            h1[(size_t)b * N1_ + j0 + 1] = fmaxf(s1 + bias1, 0.f);
        }
    }
}

// ---------------- layer 2 (class branch): h2[b][k] = relu(h1[b]·W2b[c][k] + b2b[c][k])
// grid (63, 12), block 256. 2 rows/wave, K = 1000, no LDS.
__global__ __launch_bounds__(256)
void k_l2b(const float* __restrict__ h1, const int* __restrict__ cls,
           const float* __restrict__ W2b, const float* __restrict__ b2b,
           float* __restrict__ h2) {
    const int c    = blockIdx.y;
    const int lane = threadIdx.x & 63;
    const int wave = threadIdx.x >> 6;

    const unsigned long long m = __ballot(cls[lane] == c);
    if (m == 0ull) return;

    const int j0 = blockIdx.x * 8 + wave * 2;            // 500 is even -> pair fully valid or fully out
    if (j0 >= N2_) return;

    const float4* wr0 = (const float4*)(W2b + ((size_t)c * N2_ + j0) * N1_);
    const float4* wr1 = wr0 + (N1_ / 4);                 // 250 float4 per row, 16B-aligned stride

    const float4 z4 = make_float4(0.f, 0.f, 0.f, 0.f);
    float4 w0[4], w1[4];
#pragma unroll
    for (int f = 0; f < 4; ++f) {
        const int idx = f * 64 + lane;
        const bool v = (idx < N1_ / 4);
        w0[f] = v ? wr0[idx] : z4;
        w1[f] = v ? wr1[idx] : z4;
    }
    const float bias0 = b2b[c * N2_ + j0];
    const float bias1 = b2b[c * N2_ + j0 + 1];

    for (unsigned long long mm = m; mm; mm &= (mm - 1ull)) {
        const int b = (int)__builtin_ctzll(mm);
        const float4* xr = (const float4*)(h1 + (size_t)b * N1_);
        float a0 = 0.f, a1 = 0.f;
#pragma unroll
        for (int f = 0; f < 4; ++f) {
            const int idx = f * 64 + lane;
            const float4 xv = (idx < N1_ / 4) ? xr[idx] : z4;
            a0 += w0[f].x * xv.x + w0[f].y * xv.y + w0[f].z * xv.z + w0[f].w * xv.w;
            a1 += w1[f].x * xv.x + w1[f].y * xv.y + w1[f].z * xv.z + w1[f].w * xv.w;
        }
        const float s0 = wred(a0);
        const float s1 = wred(a1);
        if (lane == 0) {
            h2[(size_t)b * N2_ + j0]     = fmaxf(s0 + bias0, 0.f);
            h2[(size_t)b * N2_ + j0 + 1] = fmaxf(s1 + bias1, 0.f);
        }
    }
}

// ---------------- layer 3 + argmax + y2 bias init
// grid 64, block 64 (one wave per b).
__global__ void k_l3b(const float* __restrict__ h2, const int* __restrict__ cls,
                      const float* __restrict__ W3b, const float* __restrict__ b3b,
                      const float* __restrict__ b2r,
                      float* __restrict__ out_y1, float* __restrict__ out_y2,
                      int* __restrict__ eb) {
    const int b    = blockIdx.x;
    const int lane = threadIdx.x;
    const int c    = cls[b];
    const float* h = h2 + (size_t)b * N2_;

    float best = -1e30f;
    int bestm = 0;
#pragma unroll 1
    for (int mI = 0; mI < NC_; ++mI) {
        const float* wrow = W3b + ((size_t)c * NC_ + mI) * N2_;
        float a = 0.f;
        for (int k = lane; k < N2_; k += 64) a += h[k] * wrow[k];
        const float s = wred(a) + b3b[c * NC_ + mI];     // identical on all lanes
        if (lane == 0) out_y1[b * NC_ + mI] = s;
        if (s > best) { best = s; bestm = mI; }          // first-occurrence argmax
    }
    const int e = c * NC_ + bestm;                        // uniform across lanes
    if (lane == 0) eb[b] = e;
    if (lane < 3) out_y2[b * 3 + lane] = b2r[e * 3 + lane];   // y2 = bias, atomics add on top
}

// ---------------- r-path layer 1 + fused tiny head via atomics
// grid (13, 64), block 256. 2 rows/wave, no LDS.
__global__ __launch_bounds__(256)
void k_l1r(const float* __restrict__ x, const int* __restrict__ eb,
           const float* __restrict__ W1r, const float* __restrict__ b1r,
           const float* __restrict__ W2r, float* __restrict__ out_y2) {
    const int b    = blockIdx.y;
    const int lane = threadIdx.x & 63;
    const int wave = threadIdx.x >> 6;

    const int j0 = blockIdx.x * 8 + wave * 2;            // 100 is even -> pair fully valid or out
    if (j0 >= N3_) return;
    const int e = eb[b];

    const float4* wr0 = (const float4*)(W1r + ((size_t)e * N3_ + j0) * N0_);
    const float4* wr1 = wr0 + (N0_ / 4);

    float4 w0[8], w1[8];
#pragma unroll
    for (int f = 0; f < 8; ++f) {
        const int idx = f * 64 + lane;
        w0[f] = wr0[idx];
        w1[f] = wr1[idx];
    }

    const float4* xr = (const float4*)(x + (size_t)b * N0_);
    float a0 = 0.f, a1 = 0.f;
#pragma unroll
    for (int f = 0; f < 8; ++f) {
        const float4 xv = xr[f * 64 + lane];
        a0 += w0[f].x * xv.x + w0[f].y * xv.y + w0[f].z * xv.z + w0[f].w * xv.w;
        a1 += w1[f].x * xv.x + w1[f].y * xv.y + w1[f].z * xv.z + w1[f].w * xv.w;
    }
    const float s0 = wred(a0);                            // full sum on all lanes
    const float s1 = wred(a1);

    const float r0 = fmaxf(s0 + b1r[e * N3_ + j0],     0.f);
    const float r1 = fmaxf(s1 + b1r[e * N3_ + j0 + 1], 0.f);

    if (lane < 3) {                                       // lane d owns output dim d
        const float* w2 = W2r + ((size_t)e * 3 + lane) * N3_;
        const float p = r0 * w2[j0] + r1 * w2[j0 + 1];
        atomicAdd(&out_y2[b * 3 + lane], p);
    }
}

extern "C" void kernel_launch(void* const* d_in, const int* in_sizes, int n_in,
                              void* d_out, int out_size, void* d_ws, size_t ws_size,
                              hipStream_t stream) {
    const float* x   = (const float*)d_in[0];
    const int*   cls = (const int*)  d_in[1];
    const float* W1b = (const float*)d_in[2];
    const float* b1b = (const float*)d_in[3];
    const float* W2b = (const float*)d_in[4];
    const float* b2b = (const float*)d_in[5];
    const float* W3b = (const float*)d_in[6];
    const float* b3b = (const float*)d_in[7];
    const float* W1r = (const float*)d_in[8];
    const float* b1r = (const float*)d_in[9];
    const float* W2r = (const float*)d_in[10];
    const float* b2r = (const float*)d_in[11];

    float* out_y1 = (float*)d_out;                 // [0, 1024)
    float* out_y2 = (float*)d_out + B_ * NC_;      // [1024, 1216)
    char*  ws  = (char*)d_ws;
    float* h1  = (float*)(ws);                     // 64*1000*4 = 256000 B
    float* h2  = (float*)(ws + 256000);            // 64*500*4  = 128000 B
    int*   eb  = (int*)  (ws + 384000);            // 64*4

    hipLaunchKernelGGL(k_l1b, dim3(125, 12), dim3(256), 0, stream, x, cls, W1b, b1b, h1);
    hipLaunchKernelGGL(k_l2b, dim3(63, 12),  dim3(256), 0, stream, h1, cls, W2b, b2b, h2);
    hipLaunchKernelGGL(k_l3b, dim3(64),      dim3(64),  0, stream, h2, cls, W3b, b3b, b2r, out_y1, out_y2, eb);
    hipLaunchKernelGGL(k_l1r, dim3(13, 64),  dim3(256), 0, stream, x, eb, W1r, b1r, W2r, out_y2);
}